// Round 14
// baseline (30.180 us; speedup 1.0000x reference)
//
#include <hip/hip_runtime.h>
#include <math.h>

#define BATCH 8192
#define NTASK 1024
#define NF 256
#define NH 64
#define MAXBLK 2816   // max sum ceil(cnt_t/4) = (8192 + 3*1024)/4

// d_ws layout (ints): [0, 4*MAXBLK) slot array (sample idx, 4 per block, int4-read)
//                     [4*MAXBLK, 5*MAXBLK) hdr per block: (task<<3)|(S-1)
//                     [5*MAXBLK] nblk

// ---------- prep: hist + nb-scan + slot-scatter + hdr, ONE block ----------
__global__ __launch_bounds__(1024) void prep_kernel(const int* __restrict__ task_ids,
                                                    int* __restrict__ slots,
                                                    int* __restrict__ hdr,
                                                    int* __restrict__ nblk) {
    __shared__ int cnt[NTASK];   // histogram, then slot cursor
    __shared__ int wsum[16];
    const int tid  = threadIdx.x;
    const int lane = tid & 63;
    const int wv   = tid >> 6;

    cnt[tid] = 0;
    __syncthreads();

    int myids[8];
    #pragma unroll
    for (int k = 0; k < 8; ++k) myids[k] = task_ids[tid + k * 1024];
    #pragma unroll
    for (int k = 0; k < 8; ++k) atomicAdd(&cnt[myids[k]], 1);
    __syncthreads();

    const int c  = cnt[tid];
    const int nb = (c + 3) >> 2;

    // inclusive wave-scan of nb (shfl, no barriers)
    int v = nb;
    #pragma unroll
    for (int d = 1; d < 64; d <<= 1) {
        int u = __shfl_up(v, d);
        if (lane >= d) v += u;
    }
    if (lane == 63) wsum[wv] = v;
    __syncthreads();
    if (wv == 0 && lane < 16) {
        int s = wsum[lane];
        #pragma unroll
        for (int d = 1; d < 16; d <<= 1) {
            int u = __shfl_up(s, d);
            if (lane >= d) s += u;
        }
        wsum[lane] = s;                   // inclusive wave sums
    }
    __syncthreads();

    const int incl   = ((wv > 0) ? wsum[wv - 1] : 0) + v;
    const int bstart = incl - nb;
    if (tid == NTASK - 1) nblk[0] = incl;
    cnt[tid] = 4 * bstart;                // cursor in SLOT space (4-aligned per block)
    __syncthreads();

    // scatter sample indices directly into descriptor slots
    #pragma unroll
    for (int k = 0; k < 8; ++k) {
        int i = tid + k * 1024;
        int pos = atomicAdd(&cnt[myids[k]], 1);
        slots[pos] = i;
    }
    // per-block header: task id + live-sample count
    for (int k = 0; k < nb; ++k) {
        int S = min(4, c - 4 * k);
        hdr[bstart + k] = (tid << 3) | (S - 1);
    }
}

// ---------- math helpers ----------
__device__ __forceinline__ float gelu_exact(float s) {
    return 0.5f * s * (1.f + erff(s * 0.70710678118654752440f));
}
__device__ __forceinline__ float4 gelu4(float4 v) {
    return make_float4(gelu_exact(v.x), gelu_exact(v.y), gelu_exact(v.z), gelu_exact(v.w));
}
__device__ __forceinline__ float4 fma4(float s, float4 w, float4 a) {
    a.x = fmaf(s, w.x, a.x); a.y = fmaf(s, w.y, a.y);
    a.z = fmaf(s, w.z, a.z); a.w = fmaf(s, w.w, a.w);
    return a;
}
__device__ __forceinline__ float4 xor_reduce4(float4 v, int m) {
    v.x += __shfl_xor(v.x, m); v.y += __shfl_xor(v.y, m);
    v.z += __shfl_xor(v.z, m); v.w += __shfl_xor(v.w, m);
    return v;
}

// ---------- main: one block per task-uniform quad of samples ----------
// Identical math/structure to R13 (absmax 0.0, W2 LDS-staged, 3 barriers).
// Only change: block prologue reads ONE int4 of sample indices + one scalar
// header -- the order[] indirection (an extra L2 round trip on every block's
// critical path) is gone.
__global__ __launch_bounds__(256) void mlp_quad(
    const float* __restrict__ x,
    const int4*  __restrict__ slots4,
    const int*   __restrict__ hdr,
    const int*   __restrict__ nblk,
    const float* __restrict__ l1_emb,
    const float* __restrict__ l2_emb,
    const float* __restrict__ l3_emb,
    float*       __restrict__ out)
{
    const int nb = nblk[0];
    const int P  = blockIdx.x;
    if (P >= nb) return;
    // bijective XCD-chunked swizzle for runtime nb (m204 variant)
    const int qc = nb >> 3, r = nb & 7;
    const int xcd = P & 7, j = P >> 3;
    const int b = (xcd < r ? xcd * (qc + 1) : r * (qc + 1) + (xcd - r) * qc) + j;

    const int  hb  = hdr[b];              // scalar load
    const int4 smp = slots4[b];           // dwordx4, independent of hb
    const int  S   = (hb & 7) + 1;
    const int  t   = hb >> 3;

    const int tid  = threadIdx.x;
    const int lane = tid & 63;
    const int w    = tid >> 6;
    const int cq   = lane & 15;
    const int grp  = lane >> 4;

    __shared__ float  xs[4][NF];        // 4 KB
    __shared__ float4 red[4][4][16];    // 4 KB  [wave][sample][quad]
    __shared__ float4 h1s[4][16];       // 1 KB  [sample][quad]
    __shared__ float4 W2s[64][16];      // 16 KB staged layer-2 panel

    // issue W2 staging loads FIRST (latency overlaps x-row load below)
    const float4* W2g = (const float4*)(l2_emb + (size_t)t * (NH * NH)); // [64][16]
    const float4 w2r0 = W2g[tid];
    const float4 w2r1 = W2g[tid + 256];
    const float4 w2r2 = W2g[tid + 512];
    const float4 w2r3 = W2g[tid + 768];

    // wave-uniform sample index: register component select, no memory access
    const int we  = min(w, S - 1);
    const int myi = (we == 0) ? smp.x : (we == 1) ? smp.y : (we == 2) ? smp.z : smp.w;

    // stage x: wave w stages its own sample's row (64 float4)
    {
        const float4* x4 = (const float4*)x;
        ((float4*)xs)[w * 64 + lane] = x4[(size_t)myi * 64 + lane];
    }
    // stage W2 into LDS (visible to all after barrier)
    {
        float4* W2f = (float4*)W2s;
        W2f[tid]       = w2r0;
        W2f[tid + 256] = w2r1;
        W2f[tid + 512] = w2r2;
        W2f[tid + 768] = w2r3;
    }
    __syncthreads();

    // ---- layer 1: wave w covers f-slice [64w, 64w+64) for ALL 4 samples ----
    const float4* W1 = (const float4*)(l1_emb + (size_t)t * (NF * NH)); // [256][16]
    float4 a0 = make_float4(0.f,0.f,0.f,0.f), a1 = a0, a2 = a0, a3 = a0;
    const int fbase = w * 64 + grp * 16;
    #pragma unroll
    for (int jj = 0; jj < 16; ++jj) {
        const int f = fbase + jj;
        float4 wv = W1[f * 16 + cq];
        a0 = fma4(xs[0][f], wv, a0);
        a1 = fma4(xs[1][f], wv, a1);
        a2 = fma4(xs[2][f], wv, a2);
        a3 = fma4(xs[3][f], wv, a3);
    }
    a0 = xor_reduce4(xor_reduce4(a0, 16), 32);   // sum over grp within wave
    a1 = xor_reduce4(xor_reduce4(a1, 16), 32);
    a2 = xor_reduce4(xor_reduce4(a2, 16), 32);
    a3 = xor_reduce4(xor_reduce4(a3, 16), 32);
    if (lane < 16) {
        red[w][0][lane] = a0; red[w][1][lane] = a1;
        red[w][2][lane] = a2; red[w][3][lane] = a3;
    }
    __syncthreads();

    // ---- finalize h1: 64 threads, one (sample, quad) each ----
    if (tid < 64) {
        int s = tid >> 4, q = tid & 15;
        float4 A = red[0][s][q], B = red[1][s][q];
        float4 C = red[2][s][q], E = red[3][s][q];
        h1s[s][q] = gelu4(make_float4(A.x+B.x+C.x+E.x, A.y+B.y+C.y+E.y,
                                      A.z+B.z+C.z+E.z, A.w+B.w+C.w+E.w));
    }
    __syncthreads();

    // ---- layer 2: wave w -> sample w; lane (grp,cq) covers rows 16grp..16grp+15 ----
    float4 acc = make_float4(0.f,0.f,0.f,0.f);
    #pragma unroll
    for (int q = 0; q < 4; ++q) {
        const float4 hv = h1s[w][4 * grp + q];   // h1 elements 16grp+4q..+3 (LDS broadcast)
        const int row = 16 * grp + 4 * q;
        acc = fma4(hv.x, W2s[row + 0][cq], acc);
        acc = fma4(hv.y, W2s[row + 1][cq], acc);
        acc = fma4(hv.z, W2s[row + 2][cq], acc);
        acc = fma4(hv.w, W2s[row + 3][cq], acc);
    }
    acc = xor_reduce4(xor_reduce4(acc, 16), 32); // sum over grp -> ALL 64 rows
    float4 g = gelu4(acc);                       // h2 col-quad cq

    // ---- layer 3 ----
    const float4* L3 = (const float4*)(l3_emb + (size_t)t * NH);
    float4 w3 = L3[cq];
    float dot = g.x * w3.x + g.y * w3.y + g.z * w3.z + g.w * w3.w;
    #pragma unroll
    for (int m = 1; m < 16; m <<= 1) dot += __shfl_xor(dot, m);
    if (lane == 0 && w < S)
        out[myi] = 1.f / (1.f + expf(-dot));
}

extern "C" void kernel_launch(void* const* d_in, const int* in_sizes, int n_in,
                              void* d_out, int out_size, void* d_ws, size_t ws_size,
                              hipStream_t stream) {
    const float* x        = (const float*)d_in[0];
    const int*   task_ids = (const int*)  d_in[1];
    const float* l1_emb   = (const float*)d_in[2];
    const float* l2_emb   = (const float*)d_in[3];
    const float* l3_emb   = (const float*)d_in[4];
    float*       out      = (float*)d_out;

    int* ws    = (int*)d_ws;
    int* slots = ws;                       // [0, 4*MAXBLK), int4-aligned
    int* hdr   = ws + 4 * MAXBLK;          // [4*MAXBLK, 5*MAXBLK)
    int* nblk  = ws + 5 * MAXBLK;

    prep_kernel<<<1, 1024, 0, stream>>>(task_ids, slots, hdr, nblk);
    mlp_quad   <<<MAXBLK, 256, 0, stream>>>(x, (const int4*)slots, hdr, nblk,
                                            l1_emb, l2_emb, l3_emb, out);
}

// Round 15
// 29.499 us; speedup vs baseline: 1.0231x; 1.0231x over previous
//
#include <hip/hip_runtime.h>
#include <math.h>

#define BATCH 8192
#define NTASK 1024
#define NF 256
#define NH 64
#define MAXBLK 2816   // max sum ceil(cnt_t/4) = (8192 + 3*1024)/4

// d_ws layout (ints): [0,8192) order | [8192, 8192+MAXBLK) desc | [8192+MAXBLK] nblk

// ---------- prep: hist + packed double-scan + scatter + desc, ONE block (R13) ----------
__global__ __launch_bounds__(1024) void prep_kernel(const int* __restrict__ task_ids,
                                                    int* __restrict__ order,
                                                    int* __restrict__ desc,
                                                    int* __restrict__ nblk) {
    __shared__ int cnt[NTASK];   // histogram, then scatter cursor
    __shared__ int wsum[16];
    const int tid  = threadIdx.x;
    const int lane = tid & 63;
    const int wv   = tid >> 6;

    cnt[tid] = 0;
    __syncthreads();

    int myids[8];
    #pragma unroll
    for (int k = 0; k < 8; ++k) myids[k] = task_ids[tid + k * 1024];
    #pragma unroll
    for (int k = 0; k < 8; ++k) atomicAdd(&cnt[myids[k]], 1);
    __syncthreads();

    const int c  = cnt[tid];
    const int nb = (c + 3) >> 2;
    const int packed = (c << 12) | nb;    // both prefix sums at once

    // inclusive wave-scan (shfl, no barriers)
    int v = packed;
    #pragma unroll
    for (int d = 1; d < 64; d <<= 1) {
        int u = __shfl_up(v, d);
        if (lane >= d) v += u;
    }
    if (lane == 63) wsum[wv] = v;
    __syncthreads();
    if (wv == 0 && lane < 16) {
        int s = wsum[lane];
        #pragma unroll
        for (int d = 1; d < 16; d <<= 1) {
            int u = __shfl_up(s, d);
            if (lane >= d) s += u;
        }
        wsum[lane] = s;                   // inclusive wave sums
    }
    __syncthreads();

    const int incl = ((wv > 0) ? wsum[wv - 1] : 0) + v;
    const int excl = incl - packed;
    const int offC   = excl >> 12;
    const int bstart = excl & 0xFFF;
    if (tid == NTASK - 1) nblk[0] = incl & 0xFFF;
    cnt[tid] = offC;                      // reuse as cursor
    __syncthreads();

    #pragma unroll
    for (int k = 0; k < 8; ++k) {
        int i = tid + k * 1024;
        int pos = atomicAdd(&cnt[myids[k]], 1);
        order[pos] = i;
    }
    for (int k = 0; k < nb; ++k) {
        int S = min(4, c - 4 * k);
        desc[bstart + k] = (tid << 15) | ((offC + 4 * k) << 2) | (S - 1);
    }
}

// ---------- math helpers ----------
__device__ __forceinline__ float gelu_exact(float s) {
    return 0.5f * s * (1.f + erff(s * 0.70710678118654752440f));
}
__device__ __forceinline__ float4 gelu4(float4 v) {
    return make_float4(gelu_exact(v.x), gelu_exact(v.y), gelu_exact(v.z), gelu_exact(v.w));
}
__device__ __forceinline__ float4 fma4(float s, float4 w, float4 a) {
    a.x = fmaf(s, w.x, a.x); a.y = fmaf(s, w.y, a.y);
    a.z = fmaf(s, w.z, a.z); a.w = fmaf(s, w.w, a.w);
    return a;
}
__device__ __forceinline__ float4 xor_reduce4(float4 v, int m) {
    v.x += __shfl_xor(v.x, m); v.y += __shfl_xor(v.y, m);
    v.z += __shfl_xor(v.z, m); v.w += __shfl_xor(v.w, m);
    return v;
}

// ---------- main: one block per task-uniform quad of samples ----------
// Exactly R13 (absmax 0.0, W2 LDS-staged, 3 barriers) + ONE change:
// the first 4 W1 quads (jj=0..3) are pre-issued before barrier 1, sharing
// the pre-barrier latency window with the W2/x staging loads, so layer 1
// starts with its first iterations' weights already in registers.
__global__ __launch_bounds__(256) void mlp_quad(
    const float* __restrict__ x,
    const int*   __restrict__ order,
    const int*   __restrict__ desc,
    const int*   __restrict__ nblk,
    const float* __restrict__ l1_emb,
    const float* __restrict__ l2_emb,
    const float* __restrict__ l3_emb,
    float*       __restrict__ out)
{
    const int nb = nblk[0];
    const int P  = blockIdx.x;
    if (P >= nb) return;
    // bijective XCD-chunked swizzle for runtime nb (m204 variant)
    const int qc = nb >> 3, r = nb & 7;
    const int xcd = P & 7, j = P >> 3;
    const int b = (xcd < r ? xcd * (qc + 1) : r * (qc + 1) + (xcd - r) * qc) + j;

    const int d  = desc[b];
    const int S  = (d & 3) + 1;
    const int st = (d >> 2) & 8191;
    const int t  = d >> 15;

    const int tid  = threadIdx.x;
    const int lane = tid & 63;
    const int w    = tid >> 6;
    const int cq   = lane & 15;
    const int grp  = lane >> 4;

    __shared__ float  xs[4][NF];        // 4 KB
    __shared__ float4 red[4][4][16];    // 4 KB  [wave][sample][quad]
    __shared__ float4 h1s[4][16];       // 1 KB  [sample][quad]
    __shared__ float4 W2s[64][16];      // 16 KB staged layer-2 panel

    // issue W2 staging loads FIRST (latency overlaps x-row load below)
    const float4* W2g = (const float4*)(l2_emb + (size_t)t * (NH * NH)); // [64][16]
    const float4 w2r0 = W2g[tid];
    const float4 w2r1 = W2g[tid + 256];
    const float4 w2r2 = W2g[tid + 512];
    const float4 w2r3 = W2g[tid + 768];

    // pre-issue the first 4 W1 quads (jj = 0..3) — same latency window
    const float4* W1 = (const float4*)(l1_emb + (size_t)t * (NF * NH)); // [256][16]
    const int fbase = w * 64 + grp * 16;
    const float4 w1p0 = W1[(fbase + 0) * 16 + cq];
    const float4 w1p1 = W1[(fbase + 1) * 16 + cq];
    const float4 w1p2 = W1[(fbase + 2) * 16 + cq];
    const float4 w1p3 = W1[(fbase + 3) * 16 + cq];

    // wave-uniform sample index (scalar load); padded waves alias sample 0
    const int myi = order[st + min(w, S - 1)];

    // stage x: wave w stages its own sample's row (64 float4)
    {
        const float4* x4 = (const float4*)x;
        ((float4*)xs)[w * 64 + lane] = x4[(size_t)myi * 64 + lane];
    }
    // stage W2 into LDS (visible to all after barrier)
    {
        float4* W2f = (float4*)W2s;
        W2f[tid]       = w2r0;
        W2f[tid + 256] = w2r1;
        W2f[tid + 512] = w2r2;
        W2f[tid + 768] = w2r3;
    }
    __syncthreads();

    // ---- layer 1: wave w covers f-slice [64w, 64w+64) for ALL 4 samples ----
    float4 a0 = make_float4(0.f,0.f,0.f,0.f), a1 = a0, a2 = a0, a3 = a0;
    // prefetched head: jj = 0..3
    {
        a0 = fma4(xs[0][fbase + 0], w1p0, a0);
        a1 = fma4(xs[1][fbase + 0], w1p0, a1);
        a2 = fma4(xs[2][fbase + 0], w1p0, a2);
        a3 = fma4(xs[3][fbase + 0], w1p0, a3);
        a0 = fma4(xs[0][fbase + 1], w1p1, a0);
        a1 = fma4(xs[1][fbase + 1], w1p1, a1);
        a2 = fma4(xs[2][fbase + 1], w1p1, a2);
        a3 = fma4(xs[3][fbase + 1], w1p1, a3);
        a0 = fma4(xs[0][fbase + 2], w1p2, a0);
        a1 = fma4(xs[1][fbase + 2], w1p2, a1);
        a2 = fma4(xs[2][fbase + 2], w1p2, a2);
        a3 = fma4(xs[3][fbase + 2], w1p2, a3);
        a0 = fma4(xs[0][fbase + 3], w1p3, a0);
        a1 = fma4(xs[1][fbase + 3], w1p3, a1);
        a2 = fma4(xs[2][fbase + 3], w1p3, a2);
        a3 = fma4(xs[3][fbase + 3], w1p3, a3);
    }
    #pragma unroll
    for (int jj = 4; jj < 16; ++jj) {
        const int f = fbase + jj;
        float4 wv = W1[f * 16 + cq];
        a0 = fma4(xs[0][f], wv, a0);
        a1 = fma4(xs[1][f], wv, a1);
        a2 = fma4(xs[2][f], wv, a2);
        a3 = fma4(xs[3][f], wv, a3);
    }
    a0 = xor_reduce4(xor_reduce4(a0, 16), 32);   // sum over grp within wave
    a1 = xor_reduce4(xor_reduce4(a1, 16), 32);
    a2 = xor_reduce4(xor_reduce4(a2, 16), 32);
    a3 = xor_reduce4(xor_reduce4(a3, 16), 32);
    if (lane < 16) {
        red[w][0][lane] = a0; red[w][1][lane] = a1;
        red[w][2][lane] = a2; red[w][3][lane] = a3;
    }
    __syncthreads();

    // ---- finalize h1: 64 threads, one (sample, quad) each ----
    if (tid < 64) {
        int s = tid >> 4, q = tid & 15;
        float4 A = red[0][s][q], B = red[1][s][q];
        float4 C = red[2][s][q], E = red[3][s][q];
        h1s[s][q] = gelu4(make_float4(A.x+B.x+C.x+E.x, A.y+B.y+C.y+E.y,
                                      A.z+B.z+C.z+E.z, A.w+B.w+C.w+E.w));
    }
    __syncthreads();

    // ---- layer 2: wave w -> sample w; lane (grp,cq) covers rows 16grp..16grp+15 ----
    float4 acc = make_float4(0.f,0.f,0.f,0.f);
    #pragma unroll
    for (int q = 0; q < 4; ++q) {
        const float4 hv = h1s[w][4 * grp + q];   // h1 elements 16grp+4q..+3 (LDS broadcast)
        const int row = 16 * grp + 4 * q;
        acc = fma4(hv.x, W2s[row + 0][cq], acc);
        acc = fma4(hv.y, W2s[row + 1][cq], acc);
        acc = fma4(hv.z, W2s[row + 2][cq], acc);
        acc = fma4(hv.w, W2s[row + 3][cq], acc);
    }
    acc = xor_reduce4(xor_reduce4(acc, 16), 32); // sum over grp -> ALL 64 rows
    float4 g = gelu4(acc);                       // h2 col-quad cq

    // ---- layer 3 ----
    const float4* L3 = (const float4*)(l3_emb + (size_t)t * NH);
    float4 w3 = L3[cq];
    float dot = g.x * w3.x + g.y * w3.y + g.z * w3.z + g.w * w3.w;
    #pragma unroll
    for (int m = 1; m < 16; m <<= 1) dot += __shfl_xor(dot, m);
    if (lane == 0 && w < S)
        out[myi] = 1.f / (1.f + expf(-dot));
}

extern "C" void kernel_launch(void* const* d_in, const int* in_sizes, int n_in,
                              void* d_out, int out_size, void* d_ws, size_t ws_size,
                              hipStream_t stream) {
    const float* x        = (const float*)d_in[0];
    const int*   task_ids = (const int*)  d_in[1];
    const float* l1_emb   = (const float*)d_in[2];
    const float* l2_emb   = (const float*)d_in[3];
    const float* l3_emb   = (const float*)d_in[4];
    float*       out      = (float*)d_out;

    int* ws    = (int*)d_ws;
    int* order = ws;                 // [0, 8192)
    int* desc  = ws + BATCH;         // [8192, 8192+MAXBLK)
    int* nblk  = ws + BATCH + MAXBLK;

    prep_kernel<<<1, 1024, 0, stream>>>(task_ids, order, desc, nblk);
    mlp_quad   <<<MAXBLK, 256, 0, stream>>>(x, order, desc, nblk,
                                            l1_emb, l2_emb, l3_emb, out);
}